// Round 4
// 170.636 us; speedup vs baseline: 1.0192x; 1.0192x over previous
//
#include <hip/hip_runtime.h>

#define BB 32
#define SS 512
#define HH 256
#define NBINS 256
#define TMAX 4096
#define ROWS_PER_BLOCK 256   // each block owns 256 consecutive frames of one batch
#define RPW 32               // rows per wave (8 waves * 32 = 256)

// Boundary i of np.linspace(vmin, vmax, 256) computed as NumPy does:
// step = (vmax-vmin)/255 (f64); b[i] = i*step + vmin (f64); b[255] = vmax.
__device__ __forceinline__ double boundary(int i, double vmin, double vmax, double step) {
    if (i == NBINS - 1) return vmax;
    return (double)i * step + vmin;
}

// searchsorted(boundaries, clip(v,vmin,vmax), side='left'), clipped to [0,255]
__device__ __forceinline__ int quantize_bin(float v, float vminf, float vmaxf) {
    v = fminf(fmaxf(v, vminf), vmaxf);
    double vd = (double)v;
    double vmin = (double)vminf, vmax = (double)vmaxf;
    double step = (vmax - vmin) / (double)(NBINS - 1);
    int g = (int)ceil((vd - vmin) / step);
    g = max(0, min(NBINS - 1, g));
    // enforce: smallest g with vd <= b[g]
    while (g > 0 && vd <= boundary(g - 1, vmin, vmax, step)) g--;
    while (g < NBINS - 1 && vd > boundary(g, vmin, vmax, step)) g++;
    return g;
}

// Fused single kernel built ONLY from round-0-proven components:
//  phase 1 (== round-0 prep, verbatim logic): 512 threads quantize all tokens
//    of batch b into LDS, Hillis-Steele scan durations into cum[512].
//  phase 2 (== round-0 prep's map write, but into LDS): threads 0..255 compute
//    packed = j | pb<<9 | eb<<17 (or -1) for this block's 256 frames.
//  phase 3 (== round-0 gather, verbatim): 8 waves x 32 rows, run-cached
//    float4 gather+add, plain coalesced stores.
// Each batch's prep is redone by its 16 blocks — trivial work, fully parallel.
__global__ __launch_bounds__(512)
void fused_kernel(const float* __restrict__ enc,
                  const float* __restrict__ pitch,
                  const float* __restrict__ energy,
                  const float* __restrict__ dur,
                  const float* __restrict__ ptab,
                  const float* __restrict__ etab,
                  float* __restrict__ out) {
    __shared__ int cum[SS];
    __shared__ int pb_sh[SS];
    __shared__ int eb_sh[SS];
    __shared__ int pk_sh[ROWS_PER_BLOCK];

    int blk  = blockIdx.x;        // 0..511
    int b    = blk >> 4;          // 16 blocks per batch
    int seg  = blk & 15;          // 256-row segment within the batch
    int row0b = seg * ROWS_PER_BLOCK;   // batch-local first frame of this block
    int s = threadIdx.x;

    // ---- phase 1: round-0 prep, verbatim ----
    int tok = b * SS + s;
    pb_sh[s] = quantize_bin(pitch[tok], 50.0f, 400.0f);
    eb_sh[s] = quantize_bin(energy[tok], 0.0f, 1.0f);
    int d = (int)rintf(dur[tok]);   // np.round: half-to-even
    if (d < 1) d = 1;
    cum[s] = d;
    __syncthreads();

    for (int off = 1; off < SS; off <<= 1) {
        int add = (s >= off) ? cum[s - off] : 0;
        __syncthreads();
        cum[s] += add;
        __syncthreads();
    }
    int total = cum[SS - 1];

    // ---- phase 2: packed map for this block's 256 frames (to LDS) ----
    if (s < ROWS_PER_BLOCK) {
        int t = row0b + s;
        int packed;
        if (t >= total) {
            packed = -1;
        } else {
            // searchsorted(cum, t, 'right') = first j with cum[j] > t
            int lo = 0, hi = SS;
            while (lo < hi) {
                int m = (lo + hi) >> 1;
                if (cum[m] <= t) lo = m + 1; else hi = m;
            }
            int j = (lo > SS - 1) ? (SS - 1) : lo;
            packed = j | (pb_sh[j] << 9) | (eb_sh[j] << 17);
        }
        pk_sh[s] = packed;
    }
    __syncthreads();

    // ---- phase 3: round-0 gather, verbatim (map entries from LDS) ----
    int wid  = s >> 6;            // 0..7
    int lane = s & 63;
    int rbase = wid * RPW;        // block-local first row of this wave

    int my_packed = (lane < RPW) ? pk_sh[rbase + lane] : 0;

    size_t grow0 = (size_t)b * TMAX + row0b + rbase;   // global first row
    int last_packed = -2;
    float4 val = make_float4(0.f, 0.f, 0.f, 0.f);
    float4* outv = reinterpret_cast<float4*>(out + grow0 * HH) + lane;

    #pragma unroll
    for (int r = 0; r < RPW; ++r) {
        int packed = __shfl(my_packed, r);
        if (packed != last_packed) {
            if (packed < 0) {
                val = make_float4(0.f, 0.f, 0.f, 0.f);
            } else {
                int j  = packed & 511;
                int pb = (packed >> 9) & 255;
                int eb = (packed >> 17) & 255;
                int tk = b * SS + j;
                const float4 e = reinterpret_cast<const float4*>(enc  + (size_t)tk * HH)[lane];
                const float4 p = reinterpret_cast<const float4*>(ptab + (size_t)pb * HH)[lane];
                const float4 q = reinterpret_cast<const float4*>(etab + (size_t)eb * HH)[lane];
                // match reference association: (enc + pt) + et
                val.x = (e.x + p.x) + q.x;
                val.y = (e.y + p.y) + q.y;
                val.z = (e.z + p.z) + q.z;
                val.w = (e.w + p.w) + q.w;
            }
            last_packed = packed;
        }
        outv[(size_t)r * (HH / 4)] = val;
    }
}

extern "C" void kernel_launch(void* const* d_in, const int* in_sizes, int n_in,
                              void* d_out, int out_size, void* d_ws, size_t ws_size,
                              hipStream_t stream) {
    const float* enc    = (const float*)d_in[0];  // [B,S,H]
    const float* pitch  = (const float*)d_in[1];  // [B,S]
    const float* energy = (const float*)d_in[2];  // [B,S]
    const float* dur    = (const float*)d_in[3];  // [B,S]
    const float* ptab   = (const float*)d_in[4];  // [256,H]
    const float* etab   = (const float*)d_in[5];  // [256,H]
    float* out = (float*)d_out;                   // [B,TMAX,H]

    int blocks = (BB * TMAX) / ROWS_PER_BLOCK;    // 512 blocks x 512 threads
    fused_kernel<<<blocks, 512, 0, stream>>>(enc, pitch, energy, dur, ptab, etab, out);
}

// Round 5
// 168.936 us; speedup vs baseline: 1.0295x; 1.0101x over previous
//
#include <hip/hip_runtime.h>

#define BB 32
#define SS 512
#define HH 256
#define NBINS 256
#define TMAX 4096
#define ROWS_PER_BLOCK 128   // each block owns 128 consecutive frames of one batch
#define RPW 16               // rows per wave (8 waves * 16 = 128)

// Boundary i of np.linspace(vmin, vmax, 256) computed as NumPy does:
// step = (vmax-vmin)/255 (f64); b[i] = i*step + vmin (f64); b[255] = vmax.
__device__ __forceinline__ double boundary(int i, double vmin, double vmax, double step) {
    if (i == NBINS - 1) return vmax;
    return (double)i * step + vmin;
}

// searchsorted(boundaries, clip(v,vmin,vmax), side='left'), clipped to [0,255]
__device__ __forceinline__ int quantize_bin(float v, float vminf, float vmaxf) {
    v = fminf(fmaxf(v, vminf), vmaxf);
    double vd = (double)v;
    double vmin = (double)vminf, vmax = (double)vmaxf;
    double step = (vmax - vmin) / (double)(NBINS - 1);
    int g = (int)ceil((vd - vmin) / step);
    g = max(0, min(NBINS - 1, g));
    // enforce: smallest g with vd <= b[g]
    while (g > 0 && vd <= boundary(g - 1, vmin, vmax, step)) g--;
    while (g < NBINS - 1 && vd > boundary(g, vmin, vmax, step)) g++;
    return g;
}

// R4-proven fused kernel, ROWS_PER_BLOCK 256 -> 128 for 2x occupancy:
//  phase 1: 512 threads quantize all tokens of batch b into LDS,
//           Hillis-Steele scan durations into cum[512]. (redundant per block,
//           fully parallel, ~2us prefix)
//  phase 2: threads 0..127 compute packed = j | pb<<9 | eb<<17 (or -1)
//           for this block's 128 frames, into LDS.
//  phase 3: 8 waves x 16 rows, run-cached float4 gather+add, plain
//           coalesced 1KB stores.
// 1024 blocks x 512 threads = up to 4 blocks/CU = 32 waves/CU (LDS 6.5KB).
__global__ __launch_bounds__(512)
void fused_kernel(const float* __restrict__ enc,
                  const float* __restrict__ pitch,
                  const float* __restrict__ energy,
                  const float* __restrict__ dur,
                  const float* __restrict__ ptab,
                  const float* __restrict__ etab,
                  float* __restrict__ out) {
    __shared__ int cum[SS];
    __shared__ int pb_sh[SS];
    __shared__ int eb_sh[SS];
    __shared__ int pk_sh[ROWS_PER_BLOCK];

    int blk  = blockIdx.x;        // 0..1023
    int b    = blk >> 5;          // 32 blocks per batch
    int seg  = blk & 31;          // 128-row segment within the batch
    int row0b = seg * ROWS_PER_BLOCK;   // batch-local first frame of this block
    int s = threadIdx.x;

    // ---- phase 1: per-token quantize + duration scan (R0/R4-proven) ----
    int tok = b * SS + s;
    pb_sh[s] = quantize_bin(pitch[tok], 50.0f, 400.0f);
    eb_sh[s] = quantize_bin(energy[tok], 0.0f, 1.0f);
    int d = (int)rintf(dur[tok]);   // np.round: half-to-even
    if (d < 1) d = 1;
    cum[s] = d;
    __syncthreads();

    for (int off = 1; off < SS; off <<= 1) {
        int add = (s >= off) ? cum[s - off] : 0;
        __syncthreads();
        cum[s] += add;
        __syncthreads();
    }
    int total = cum[SS - 1];

    // ---- phase 2: packed map for this block's 128 frames (to LDS) ----
    if (s < ROWS_PER_BLOCK) {
        int t = row0b + s;
        int packed;
        if (t >= total) {
            packed = -1;
        } else {
            // searchsorted(cum, t, 'right') = first j with cum[j] > t
            int lo = 0, hi = SS;
            while (lo < hi) {
                int m = (lo + hi) >> 1;
                if (cum[m] <= t) lo = m + 1; else hi = m;
            }
            int j = (lo > SS - 1) ? (SS - 1) : lo;
            packed = j | (pb_sh[j] << 9) | (eb_sh[j] << 17);
        }
        pk_sh[s] = packed;
    }
    __syncthreads();

    // ---- phase 3: run-cached gather + coalesced stores (R0/R4-proven) ----
    int wid  = s >> 6;            // 0..7
    int lane = s & 63;
    int rbase = wid * RPW;        // block-local first row of this wave

    int my_packed = (lane < RPW) ? pk_sh[rbase + lane] : 0;

    size_t grow0 = (size_t)b * TMAX + row0b + rbase;   // global first row
    int last_packed = -2;
    float4 val = make_float4(0.f, 0.f, 0.f, 0.f);
    float4* outv = reinterpret_cast<float4*>(out + grow0 * HH) + lane;

    #pragma unroll
    for (int r = 0; r < RPW; ++r) {
        int packed = __shfl(my_packed, r);
        if (packed != last_packed) {
            if (packed < 0) {
                val = make_float4(0.f, 0.f, 0.f, 0.f);
            } else {
                int j  = packed & 511;
                int pb = (packed >> 9) & 255;
                int eb = (packed >> 17) & 255;
                int tk = b * SS + j;
                const float4 e = reinterpret_cast<const float4*>(enc  + (size_t)tk * HH)[lane];
                const float4 p = reinterpret_cast<const float4*>(ptab + (size_t)pb * HH)[lane];
                const float4 q = reinterpret_cast<const float4*>(etab + (size_t)eb * HH)[lane];
                // match reference association: (enc + pt) + et
                val.x = (e.x + p.x) + q.x;
                val.y = (e.y + p.y) + q.y;
                val.z = (e.z + p.z) + q.z;
                val.w = (e.w + p.w) + q.w;
            }
            last_packed = packed;
        }
        outv[(size_t)r * (HH / 4)] = val;
    }
}

extern "C" void kernel_launch(void* const* d_in, const int* in_sizes, int n_in,
                              void* d_out, int out_size, void* d_ws, size_t ws_size,
                              hipStream_t stream) {
    const float* enc    = (const float*)d_in[0];  // [B,S,H]
    const float* pitch  = (const float*)d_in[1];  // [B,S]
    const float* energy = (const float*)d_in[2];  // [B,S]
    const float* dur    = (const float*)d_in[3];  // [B,S]
    const float* ptab   = (const float*)d_in[4];  // [256,H]
    const float* etab   = (const float*)d_in[5];  // [256,H]
    float* out = (float*)d_out;                   // [B,TMAX,H]

    int blocks = (BB * TMAX) / ROWS_PER_BLOCK;    // 1024 blocks x 512 threads
    fused_kernel<<<blocks, 512, 0, stream>>>(enc, pitch, energy, dur, ptab, etab, out);
}